// Round 1
// 159.810 us; speedup vs baseline: 1.0375x; 1.0375x over previous
//
#include <hip/hip_runtime.h>

#define B_ 32
#define S_ 64
#define H_ 300
#define H2_ 600
#define L_ 20
#define ROW_ 160                    // 8 pieces * 20
#define OUTQ_OFF ((size_t)B_ * S_ * ROW_)
#define NEG_INF -3.402823466e38f

typedef __attribute__((ext_vector_type(8))) _Float16 half8v;   // 8 f16 = 4 VGPRs
typedef __attribute__((ext_vector_type(4))) _Float16 half4v;   // 4 f16 = 8 B
typedef __attribute__((ext_vector_type(4))) float float4v;

// ---------------- K0: w1 (|W|), w2r (W^2, row layout), zero sum_p, row norms.
// One wave per (p|q, bd, s) row: float4 loads + shuffle reduce. 2048 blocks.
__global__ __launch_bounds__(256) void k_pre(const float* __restrict__ Wf,
                                             const float* __restrict__ P,
                                             const float* __restrict__ Q,
                                             float* __restrict__ w2r,
                                             float* __restrict__ w1,
                                             float* __restrict__ sum_p,
                                             float* __restrict__ pn_g,
                                             float* __restrict__ qn_g) {
  int t = threadIdx.x;
  int i = blockIdx.x * 256 + t;
  if (i < 8 * L_ * H_) {
    float v = Wf[i];
    w1[i] = fabsf(v);
    w2r[i] = v * v;
  }
  if (i < B_ * 2 * S_) sum_p[i] = 0.f;
  int rid = blockIdx.x * 4 + (t >> 6);   // 0..8191
  int lane = t & 63;
  int isQ = rid >= 4096;
  int r2 = rid & 4095;
  int bd = r2 >> 6, s = r2 & 63;
  int b = bd >> 1, dir = bd & 1;
  const float* base = (isQ ? Q : P) + (size_t)b * S_ * H2_ + (size_t)s * H2_ + dir * H_;
  float4v v4 = *(const float4v*)&base[4 * lane];               // cols 0..255
  float acc = v4.x * v4.x + v4.y * v4.y + v4.z * v4.z + v4.w * v4.w;
  if (lane < 11) {                                             // cols 256..299
    float4v u4 = *(const float4v*)&base[256 + 4 * lane];
    acc += u4.x * u4.x + u4.y * u4.y + u4.z * u4.z + u4.w * u4.w;
  }
#pragma unroll
  for (int m = 1; m < 64; m <<= 1) acc += __shfl_xor(acc, m);
  if (lane == 0) (isQ ? qn_g : pn_g)[r2] = sqrtf(acc);
}

// ---------------- K1: cosine matrix. Norms precomputed; float4 staging;
// conflict-free strides (101: gcd(13,32)=1); shuffle row-sums; LDS col-partials.
struct CosS {
  float xq[S_][101];     // 25856 B, stride 101 -> conflict-free column reads
  float xp[16][104];     // 6656 B, 16B-aligned rows, broadcast reads
  float colpart[4][S_];  // per-wave column-sum partials
  float pn_l[16], qn_l[S_];
};

__global__ __launch_bounds__(256) void k_cos(const float* __restrict__ P,
                                             const float* __restrict__ Q,
                                             const float* __restrict__ pn_g,
                                             const float* __restrict__ qn_g,
                                             float* __restrict__ cosM,
                                             float* __restrict__ sum_p,
                                             float* __restrict__ sum_q) {
  __shared__ CosS S;
  int bd = blockIdx.x, pg = blockIdx.y, p0 = pg * 16;
  int b = bd >> 1, dir = bd & 1;
  int t = threadIdx.x;
  int q = t & 63, pr = t >> 6;
  const float* Pb = P + (size_t)b * S_ * H2_ + dir * H_;
  const float* Qb = Q + (size_t)b * S_ * H2_ + dir * H_;
  if (t < 16) S.pn_l[t] = pn_g[bd * S_ + p0 + t];
  else if (t >= 64 && t < 128) S.qn_l[t - 64] = qn_g[bd * S_ + (t - 64)];
  float dot0 = 0.f, dot1 = 0.f, dot2 = 0.f, dot3 = 0.f;
  for (int c0 = 0; c0 < H_; c0 += 100) {
    __syncthreads();
    for (int idx = t; idx < S_ * 25; idx += 256) {
      int s = idx / 25, g = idx - s * 25;
      float4v v = *(const float4v*)&Qb[(size_t)s * H2_ + c0 + 4 * g];
      S.xq[s][4 * g + 0] = v.x; S.xq[s][4 * g + 1] = v.y;
      S.xq[s][4 * g + 2] = v.z; S.xq[s][4 * g + 3] = v.w;
    }
    for (int idx = t; idx < 16 * 25; idx += 256) {
      int s = idx / 25, g = idx - s * 25;
      *(float4v*)&S.xp[s][4 * g] = *(const float4v*)&Pb[(size_t)(p0 + s) * H2_ + c0 + 4 * g];
    }
    __syncthreads();
    for (int hh = 0; hh < 100; hh += 4) {
      float qv0 = S.xq[q][hh + 0];
      float qv1 = S.xq[q][hh + 1];
      float qv2 = S.xq[q][hh + 2];
      float qv3 = S.xq[q][hh + 3];
      float4v av0 = *(const float4v*)&S.xp[4 * pr + 0][hh];
      float4v av1 = *(const float4v*)&S.xp[4 * pr + 1][hh];
      float4v av2 = *(const float4v*)&S.xp[4 * pr + 2][hh];
      float4v av3 = *(const float4v*)&S.xp[4 * pr + 3][hh];
      dot0 = fmaf(av0.x, qv0, dot0); dot0 = fmaf(av0.y, qv1, dot0);
      dot0 = fmaf(av0.z, qv2, dot0); dot0 = fmaf(av0.w, qv3, dot0);
      dot1 = fmaf(av1.x, qv0, dot1); dot1 = fmaf(av1.y, qv1, dot1);
      dot1 = fmaf(av1.z, qv2, dot1); dot1 = fmaf(av1.w, qv3, dot1);
      dot2 = fmaf(av2.x, qv0, dot2); dot2 = fmaf(av2.y, qv1, dot2);
      dot2 = fmaf(av2.z, qv2, dot2); dot2 = fmaf(av2.w, qv3, dot2);
      dot3 = fmaf(av3.x, qv0, dot3); dot3 = fmaf(av3.y, qv1, dot3);
      dot3 = fmaf(av3.z, qv2, dot3); dot3 = fmaf(av3.w, qv3, dot3);
    }
  }
  float qn = S.qn_l[q];
  float* cm = cosM + (size_t)bd * S_ * S_;
  float dots[4] = {dot0, dot1, dot2, dot3};
  float colacc = 0.f;
#pragma unroll
  for (int i2 = 0; i2 < 4; ++i2) {
    int p = 4 * pr + i2;
    float c = dots[i2] / (S.pn_l[p] * qn);
    cm[(size_t)(p0 + p) * S_ + q] = c;
    colacc += c;
    float rs = c;
#pragma unroll
    for (int m = 1; m < 64; m <<= 1) rs += __shfl_xor(rs, m);
    if (q == 0) sum_q[bd * S_ + p0 + p] = rs;
  }
  S.colpart[pr][q] = colacc;
  __syncthreads();
  if (t < S_) {
    float cs = S.colpart[0][t] + S.colpart[1][t] + S.colpart[2][t] + S.colpart[3][t];
    atomicAdd(&sum_p[bd * S_ + t], cs);
  }
}

// ======== fused main kernel
#define HP 72                       // padded fp16 row: 144 B, 16-B aligned f16x8 groups
struct MaxpoolS {                   // ~21.2 KB
  _Float16 ph[S_][HP];
  _Float16 qh[S_][HP];
  float w1s[H_];
  float pn2[S_], qn2[S_];
  float colp[4][S_];
};
#define SG 4
struct OutsS {                      // 31264 B (occupancy bound: 5/CU)
  float u[600];
  float xP[SG][H_], xQ[SG][H_];
  float vmq[SG][H_], vmp[SG][H_], vxq[SG][H_], vxp[SG][H_];
  float sps[SG], sqs[SG];
};

__device__ __forceinline__ void maxpool_body(char* smem, int bid,
                                             const float* __restrict__ P,
                                             const float* __restrict__ Q,
                                             const float* __restrict__ w1,
                                             float* __restrict__ out) {
  MaxpoolS& S = *(MaxpoolS*)smem;
  // XCD swizzle: bd = (bid&7) + 8*((bid>>3)&7); l = bid>>6
  int x = bid & 7, j = bid >> 3;
  int bd = x + 8 * (j & 7);
  int l = j >> 3;
  int b = bd >> 1, dir = bd & 1;
  int t = threadIdx.x;
  int w = t >> 6, lane = t & 63, quad = lane >> 4, col = lane & 15;
  const float* w1g = w1 + (size_t)(2 + dir) * L_ * H_ + (size_t)l * H_;
  if (t < 75) *(float4v*)&S.w1s[4 * t] = *(const float4v*)&w1g[4 * t];
  const float* Pb = P + (size_t)b * S_ * H2_ + dir * H_;
  const float* Qb = Q + (size_t)b * S_ * H2_ + dir * H_;
  float4v acc[4];
#pragma unroll
  for (int qt = 0; qt < 4; ++qt) acc[qt] = (float4v){0.f, 0.f, 0.f, 0.f};
  float np2a[4] = {0.f, 0.f, 0.f, 0.f};
  float nq2a[4] = {0.f, 0.f, 0.f, 0.f};
  for (int h0 = 0; h0 < H_; h0 += 64) {          // 5 chunks (last zero-padded)
    __syncthreads();
#pragma unroll
    for (int jj = 0; jj < 4; ++jj) {             // float4 staging: 4 iters/chunk
      int idx = t + 256 * jj;
      int s = idx >> 4, c4 = idx & 15;
      int h = h0 + 4 * c4;
      float4v pv = {0.f, 0.f, 0.f, 0.f}, qv = {0.f, 0.f, 0.f, 0.f};
      if (h < 297) {                             // full group valid (h+3 <= 299)
        float4v wv = *(const float4v*)&S.w1s[h];
        float4v p4 = *(const float4v*)&Pb[(size_t)s * H2_ + h];
        float4v q4 = *(const float4v*)&Qb[(size_t)s * H2_ + h];
        pv = p4 * wv;
        qv = q4 * wv;
      }
      half4v phv = __builtin_convertvector(pv, half4v);
      half4v qhv = __builtin_convertvector(qv, half4v);
      *(half4v*)&S.ph[s][4 * c4] = phv;
      *(half4v*)&S.qh[s][4 * c4] = qhv;
      // norms from the SAME fp16 values (consistent with MFMA numerator)
      float4v pf = __builtin_convertvector(phv, float4v);
      float4v qf = __builtin_convertvector(qhv, float4v);
      np2a[jj] += pf.x * pf.x + pf.y * pf.y + pf.z * pf.z + pf.w * pf.w;
      nq2a[jj] += qf.x * qf.x + qf.y * qf.y + qf.z * qf.z + qf.w * qf.w;
    }
    __syncthreads();
#pragma unroll
    for (int ks = 0; ks < 2; ++ks) {
      half8v ah = *(const half8v*)&S.ph[16 * w + col][ks * 32 + quad * 8];
#pragma unroll
      for (int qt = 0; qt < 4; ++qt) {
        half8v bh = *(const half8v*)&S.qh[16 * qt + col][ks * 32 + quad * 8];
        acc[qt] = __builtin_amdgcn_mfma_f32_16x16x32_f16(ah, bh, acc[qt], 0, 0, 0);
      }
    }
  }
  // reduce norm partials once (16-lane groups cover the 64 cols of each chunk)
#pragma unroll
  for (int jj = 0; jj < 4; ++jj) {
    float a = np2a[jj], bb = nq2a[jj];
#pragma unroll
    for (int m = 1; m < 16; m <<= 1) {
      a += __shfl_xor(a, m);
      bb += __shfl_xor(bb, m);
    }
    if ((t & 15) == 0) {
      int s = (t >> 4) + 16 * jj;
      S.pn2[s] = a;
      S.qn2[s] = bb;
    }
  }
  __syncthreads();
  // C/D: row = quad*4+r (p_local), col = lane&15 (q_local) [m89/m91 verified]
  float pnv[4];
#pragma unroll
  for (int r = 0; r < 4; ++r) pnv[r] = sqrtf(S.pn2[16 * w + quad * 4 + r]);
  float rowm[4] = {NEG_INF, NEG_INF, NEG_INF, NEG_INF};
#pragma unroll
  for (int qt = 0; qt < 4; ++qt) {
    float qnv = sqrtf(S.qn2[16 * qt + col]);
    float cmv = NEG_INF;
#pragma unroll
    for (int r = 0; r < 4; ++r) {
      float c = acc[qt][r] / (pnv[r] * qnv);    // no EPS in reference maxpool
      rowm[r] = fmaxf(rowm[r], c);
      cmv = fmaxf(cmv, c);
    }
    cmv = fmaxf(cmv, __shfl_xor(cmv, 16));
    cmv = fmaxf(cmv, __shfl_xor(cmv, 32));
    if (quad == 0) S.colp[w][16 * qt + col] = cmv;
  }
#pragma unroll
  for (int m = 1; m < 16; m <<= 1)
#pragma unroll
    for (int r = 0; r < 4; ++r) rowm[r] = fmaxf(rowm[r], __shfl_xor(rowm[r], m));
  if (col == 0) {
#pragma unroll
    for (int r = 0; r < 4; ++r) {
      int p = 16 * w + quad * 4 + r;
      out[((size_t)b * S_ + p) * ROW_ + (2 + dir) * L_ + l] = rowm[r];
    }
  }
  __syncthreads();
  if (t < S_) {
    float m0 = fmaxf(fmaxf(S.colp[0][t], S.colp[1][t]), fmaxf(S.colp[2][t], S.colp[3][t]));
    out[OUTQ_OFF + ((size_t)b * S_ + t) * ROW_ + (2 + dir) * L_ + l] = m0;
  }
}

__device__ __forceinline__ void outs_body(char* smem, int bid,
                                          const float* __restrict__ P,
                                          const float* __restrict__ Q,
                                          const float* __restrict__ w2r,
                                          const float* __restrict__ cosM,
                                          const float* __restrict__ sum_p,
                                          const float* __restrict__ sum_q,
                                          float* __restrict__ out) {
  OutsS& S = *(OutsS*)smem;
  // XCD swizzle: bd = (bid&7) + 8*((bid>>3)&7); sg = bid>>6
  int x = bid & 7, j = bid >> 3;
  int bd = x + 8 * (j & 7);
  int sg = j >> 3;
  int s0 = sg * SG;
  int b = bd >> 1, dir = bd & 1;
  int t = threadIdx.x;
  // cos staged TRANSPOSED + interleaved: cosT[k][si] = cosC, cosT[k][4+si] = cosR
  // -> k-loop reads 2 broadcast b128 instead of 8 scalar LDS per k.
  float (*cosT)[8] = (float (*)[8])&S.u[0];     // 512 floats in u[600]
  const float* cm = cosM + (size_t)bd * S_ * S_;
  for (int idx = t; idx < S_ * 8; idx += 256) {
    int k = idx >> 3, jj = idx & 7, si = jj & 3;
    cosT[k][jj] = (jj < 4) ? cm[(size_t)k * S_ + s0 + si]
                           : cm[(size_t)(s0 + si) * S_ + k];
  }
  if (t < SG) { S.sps[t] = sum_p[bd * S_ + s0 + t]; S.sqs[t] = sum_q[bd * S_ + s0 + t]; }
  int tgt = dir ? 0 : S_ - 1;
  const float* Pb = P + (size_t)b * S_ * H2_ + dir * H_;
  const float* Qb = Q + (size_t)b * S_ * H2_ + dir * H_;
  for (int g = t; g < SG * 75; g += 256) {
    int si = g / 75, c4 = g - si * 75;
    *(float4v*)&S.xP[si][4 * c4] = *(const float4v*)&Pb[(size_t)(s0 + si) * H2_ + 4 * c4];
    *(float4v*)&S.xQ[si][4 * c4] = *(const float4v*)&Qb[(size_t)(s0 + si) * H2_ + 4 * c4];
  }
  __syncthreads();
  for (int h = t; h < H_; h += 256) {
    float amp[SG], amq[SG], axp[SG], axq[SG];
#pragma unroll
    for (int si = 0; si < SG; ++si) { amp[si] = 0.f; amq[si] = 0.f; axp[si] = NEG_INF; axq[si] = NEG_INF; }
    for (int k = 0; k < S_; k += 2) {
      float pv0 = Pb[(size_t)k * H2_ + h];
      float qv0 = Qb[(size_t)k * H2_ + h];
      float pv1 = Pb[(size_t)(k + 1) * H2_ + h];
      float qv1 = Qb[(size_t)(k + 1) * H2_ + h];
      float4v cc0 = *(const float4v*)&cosT[k][0];
      float4v cr0 = *(const float4v*)&cosT[k][4];
      float4v cc1 = *(const float4v*)&cosT[k + 1][0];
      float4v cr1 = *(const float4v*)&cosT[k + 1][4];
#pragma unroll
      for (int si = 0; si < SG; ++si) {
        float t1 = pv0 * cc0[si];
        amp[si] += t1; axp[si] = fmaxf(axp[si], t1);
        float t2 = qv0 * cr0[si];
        amq[si] += t2; axq[si] = fmaxf(axq[si], t2);
        float t3 = pv1 * cc1[si];
        amp[si] += t3; axp[si] = fmaxf(axp[si], t3);
        float t4 = qv1 * cr1[si];
        amq[si] += t4; axq[si] = fmaxf(axq[si], t4);
      }
    }
#pragma unroll
    for (int si = 0; si < SG; ++si) {
      S.vmq[si][h] = amq[si] / S.sqs[si];
      S.vmp[si][h] = amp[si] / S.sps[si];
      S.vxq[si][h] = axq[si];
      S.vxp[si][h] = axp[si];
    }
  }
  __syncthreads();
  float* tq = &S.u[0];
  float* tp = &S.u[300];
  if (t < 75) {
    *(float4v*)&tq[4 * t] = *(const float4v*)&Qb[(size_t)tgt * H2_ + 4 * t];
    *(float4v*)&tp[4 * t] = *(const float4v*)&Pb[(size_t)tgt * H2_ + 4 * t];
  }
  __syncthreads();
  if (t < 240) {
    const int wb_[6] = {0, 0, 4, 4, 6, 6};
#pragma unroll
    for (int r = 0; r < 2; ++r) {
      int job = t + 240 * r;
      int l = job % L_;
      int g = job / L_;
      int pr = g % 6, si = g / 6;
      const float* xv = (pr & 1) ? S.xQ[si] : S.xP[si];
      const float* y;
      if (pr == 0) y = tq;
      else if (pr == 1) y = tp;
      else if (pr == 2) y = S.vmq[si];
      else if (pr == 3) y = S.vmp[si];
      else if (pr == 4) y = S.vxq[si];
      else y = S.vxp[si];
      int widx = wb_[pr] + dir;
      const float* wp = w2r + (size_t)widx * (L_ * H_) + (size_t)l * H_;   // row layout
      float a1 = 0.f, a2 = 0.f, a3 = 0.f;
      for (int h4 = 0; h4 < H_; h4 += 4) {
        float4v wv = *(const float4v*)&wp[h4];
        float4v xx = *(const float4v*)&xv[h4];
        float4v yy = *(const float4v*)&y[h4];
#pragma unroll
        for (int jj = 0; jj < 4; ++jj) {
          float wx = wv[jj] * xx[jj];
          a1 = fmaf(wx, yy[jj], a1);
          a2 = fmaf(wx, xx[jj], a2);
          a3 = fmaf(wv[jj] * yy[jj], yy[jj], a3);
        }
      }
      float den = fmaxf(sqrtf(a2) * sqrtf(a3), 1e-8f);   // EPS per _mp_cos
      float c = a1 / den;
      int s = s0 + si;
      size_t base = ((pr & 1) ? OUTQ_OFF : 0) + ((size_t)b * S_ + s) * ROW_;
      out[base + (size_t)widx * L_ + l] = c;
    }
  }
}

__global__ __launch_bounds__(256) void k_main(const float* __restrict__ P,
                                              const float* __restrict__ Q,
                                              const float* __restrict__ w1,
                                              const float* __restrict__ w2r,
                                              const float* __restrict__ cosM,
                                              const float* __restrict__ sum_p,
                                              const float* __restrict__ sum_q,
                                              float* __restrict__ out) {
  extern __shared__ char smem[];
  int bid = blockIdx.x;
  if (bid < B_ * 2 * L_) maxpool_body(smem, bid, P, Q, w1, out);
  else outs_body(smem, bid - B_ * 2 * L_, P, Q, w2r, cosM, sum_p, sum_q, out);
}

extern "C" void kernel_launch(void* const* d_in, const int* in_sizes, int n_in,
                              void* d_out, int out_size, void* d_ws, size_t ws_size,
                              hipStream_t stream) {
  (void)out_size; (void)ws_size;
  int iw = 2;
  for (int i = 0; i < n_in; ++i) if (in_sizes[i] == 8 * L_ * H_) iw = i;
  int io[2] = {0, 1}, k = 0;
  for (int i = 0; i < n_in && k < 2; ++i) if (i != iw) io[k++] = i;
  const float* P  = (const float*)d_in[io[0]];
  const float* Q  = (const float*)d_in[io[1]];
  const float* Wf = (const float*)d_in[iw];
  float* out = (float*)d_out;

  float* ws = (float*)d_ws;         // ~1.50 MB
  float* w2r   = ws;                // 48000
  float* w1    = w2r + 48000;       // 48000
  float* cosM  = w1 + 48000;        // 262144
  float* sum_p = cosM + 262144;     // 4096 (zeroed by k_pre, atomic target)
  float* sum_q = sum_p + 4096;      // 4096
  float* pn_g  = sum_q + 4096;      // 4096 row norms (P halves)
  float* qn_g  = pn_g + 4096;       // 4096 row norms (Q halves)

  size_t shbytes = sizeof(MaxpoolS) > sizeof(OutsS) ? sizeof(MaxpoolS) : sizeof(OutsS);
  k_pre<<<2048, 256, 0, stream>>>(Wf, P, Q, w2r, w1, sum_p, pn_g, qn_g);
  k_cos<<<dim3(B_ * 2, 4), 256, 0, stream>>>(P, Q, pn_g, qn_g, cosM, sum_p, sum_q);
  k_main<<<B_ * 2 * L_ + B_ * 2 * 16, 256, shbytes, stream>>>(P, Q, w1, w2r, cosM, sum_p, sum_q, out);
}

// Round 2
// 144.108 us; speedup vs baseline: 1.1505x; 1.1090x over previous
//
#include <hip/hip_runtime.h>

#define B_ 32
#define S_ 64
#define H_ 300
#define H2_ 600
#define L_ 20
#define ROW_ 160                    // 8 pieces * 20
#define OUTQ_OFF ((size_t)B_ * S_ * ROW_)
#define NEG_INF -3.402823466e38f

#define NB_COS 1024                 // 64 bd * 16 pg (4 p-rows each)
#define NB_W 188                    // 48000 / 256 rounded up
#define NB_MP 1280                  // 64 bd * 20 l

typedef __attribute__((ext_vector_type(8))) _Float16 half8v;   // 8 f16 = 4 VGPRs
typedef __attribute__((ext_vector_type(4))) _Float16 half4v;   // 4 f16 = 8 B
typedef __attribute__((ext_vector_type(4))) float float4v;

// ---------------- cos block: (bd, pg) -> 4 p-rows x 64 q, norms in-block.
struct CosS {                       // 28800 B -> 5 blocks/CU
  float xq[S_][101];                // stride 101: gcd(5,32)=1 -> 2-way reads (free)
  float xp[4][104];                 // 16B-aligned rows, broadcast b128 reads
  float qn_l[S_];
  float cp[4][S_];
};

__device__ __forceinline__ void cos_body(char* smem, int bid,
                                         const float* __restrict__ P,
                                         const float* __restrict__ Q,
                                         float* __restrict__ cosM,
                                         float* __restrict__ sumpart,
                                         float* __restrict__ sum_q) {
  CosS& S = *(CosS*)smem;
  int bd = bid >> 4, pg = bid & 15;
  int b = bd >> 1, dir = bd & 1;
  int t = threadIdx.x;
  int q = t & 63, pr = t >> 6;
  const float* Pb = P + (size_t)b * S_ * H2_ + dir * H_;
  const float* Qb = Q + (size_t)b * S_ * H2_ + dir * H_;
  float dot = 0.f, np2 = 0.f, nq2 = 0.f;
  for (int c0 = 0; c0 < H_; c0 += 100) {
    __syncthreads();
    for (int idx = t; idx < S_ * 25; idx += 256) {
      int s = idx / 25, g = idx - s * 25;
      float4v v = *(const float4v*)&Qb[(size_t)s * H2_ + c0 + 4 * g];
      S.xq[s][4 * g + 0] = v.x; S.xq[s][4 * g + 1] = v.y;
      S.xq[s][4 * g + 2] = v.z; S.xq[s][4 * g + 3] = v.w;
    }
    if (t < 100) {
      int s = t / 25, g = t - (t / 25) * 25;
      *(float4v*)&S.xp[s][4 * g] =
          *(const float4v*)&Pb[(size_t)(pg * 4 + s) * H2_ + c0 + 4 * g];
    }
    __syncthreads();
    for (int hh = 0; hh < 100; hh += 4) {
      float4v av = *(const float4v*)&S.xp[pr][hh];       // wave-broadcast (free)
      float q0 = S.xq[q][hh + 0];
      float q1 = S.xq[q][hh + 1];
      float q2 = S.xq[q][hh + 2];
      float q3 = S.xq[q][hh + 3];
      dot = fmaf(av.x, q0, dot); dot = fmaf(av.y, q1, dot);
      dot = fmaf(av.z, q2, dot); dot = fmaf(av.w, q3, dot);
      np2 = fmaf(av.x, av.x, np2); np2 = fmaf(av.y, av.y, np2);
      np2 = fmaf(av.z, av.z, np2); np2 = fmaf(av.w, av.w, np2);
      if (pr == 0) {                                     // wave-uniform branch
        nq2 = fmaf(q0, q0, nq2); nq2 = fmaf(q1, q1, nq2);
        nq2 = fmaf(q2, q2, nq2); nq2 = fmaf(q3, q3, nq2);
      }
    }
  }
  if (pr == 0) S.qn_l[q] = sqrtf(nq2);
  __syncthreads();
  float pn = sqrtf(np2);                                 // uniform per wave
  float c = dot / (pn * S.qn_l[q]);
  int p = pg * 4 + pr;
  cosM[(size_t)bd * S_ * S_ + (size_t)p * S_ + q] = c;
  float rs = c;
#pragma unroll
  for (int m = 1; m < 64; m <<= 1) rs += __shfl_xor(rs, m);
  if (q == 0) sum_q[bd * S_ + p] = rs;
  S.cp[pr][q] = c;
  __syncthreads();
  if (t < S_)
    sumpart[((size_t)bd * 16 + pg) * S_ + t] =
        S.cp[0][t] + S.cp[1][t] + S.cp[2][t] + S.cp[3][t];
}

// ---------------- maxpool block (independent: |W| taken straight from Wf)
#define HP 72                       // padded fp16 row: 144 B, 16-B aligned f16x8 groups
struct MaxpoolS {                   // ~21.2 KB
  _Float16 ph[S_][HP];
  _Float16 qh[S_][HP];
  float w1s[H_];
  float pn2[S_], qn2[S_];
  float colp[4][S_];
};

__device__ __forceinline__ void maxpool_body(char* smem, int bid,
                                             const float* __restrict__ P,
                                             const float* __restrict__ Q,
                                             const float* __restrict__ Wf,
                                             float* __restrict__ out) {
  MaxpoolS& S = *(MaxpoolS*)smem;
  // XCD swizzle: bd = (bid&7) + 8*((bid>>3)&7); l = bid>>6
  int x = bid & 7, j = bid >> 3;
  int bd = x + 8 * (j & 7);
  int l = j >> 3;
  int b = bd >> 1, dir = bd & 1;
  int t = threadIdx.x;
  int w = t >> 6, lane = t & 63, quad = lane >> 4, col = lane & 15;
  const float* wg = Wf + (size_t)(2 + dir) * L_ * H_ + (size_t)l * H_;
  if (t < 75) {
    float4v v = *(const float4v*)&wg[4 * t];
    float4v a = {fabsf(v.x), fabsf(v.y), fabsf(v.z), fabsf(v.w)};
    *(float4v*)&S.w1s[4 * t] = a;
  }
  const float* Pb = P + (size_t)b * S_ * H2_ + dir * H_;
  const float* Qb = Q + (size_t)b * S_ * H2_ + dir * H_;
  float4v acc[4];
#pragma unroll
  for (int qt = 0; qt < 4; ++qt) acc[qt] = (float4v){0.f, 0.f, 0.f, 0.f};
  float np2a[4] = {0.f, 0.f, 0.f, 0.f};
  float nq2a[4] = {0.f, 0.f, 0.f, 0.f};
  for (int h0 = 0; h0 < H_; h0 += 64) {          // 5 chunks (last zero-padded)
    __syncthreads();
#pragma unroll
    for (int jj = 0; jj < 4; ++jj) {             // float4 staging: 4 iters/chunk
      int idx = t + 256 * jj;
      int s = idx >> 4, c4 = idx & 15;
      int h = h0 + 4 * c4;
      float4v pv = {0.f, 0.f, 0.f, 0.f}, qv = {0.f, 0.f, 0.f, 0.f};
      if (h < 297) {                             // full group valid (h+3 <= 299)
        float4v wv = *(const float4v*)&S.w1s[h];
        float4v p4 = *(const float4v*)&Pb[(size_t)s * H2_ + h];
        float4v q4 = *(const float4v*)&Qb[(size_t)s * H2_ + h];
        pv = p4 * wv;
        qv = q4 * wv;
      }
      half4v phv = __builtin_convertvector(pv, half4v);
      half4v qhv = __builtin_convertvector(qv, half4v);
      *(half4v*)&S.ph[s][4 * c4] = phv;
      *(half4v*)&S.qh[s][4 * c4] = qhv;
      // norms from the SAME fp16 values (consistent with MFMA numerator)
      float4v pf = __builtin_convertvector(phv, float4v);
      float4v qf = __builtin_convertvector(qhv, float4v);
      np2a[jj] += pf.x * pf.x + pf.y * pf.y + pf.z * pf.z + pf.w * pf.w;
      nq2a[jj] += qf.x * qf.x + qf.y * qf.y + qf.z * qf.z + qf.w * qf.w;
    }
    __syncthreads();
#pragma unroll
    for (int ks = 0; ks < 2; ++ks) {
      half8v ah = *(const half8v*)&S.ph[16 * w + col][ks * 32 + quad * 8];
#pragma unroll
      for (int qt = 0; qt < 4; ++qt) {
        half8v bh = *(const half8v*)&S.qh[16 * qt + col][ks * 32 + quad * 8];
        acc[qt] = __builtin_amdgcn_mfma_f32_16x16x32_f16(ah, bh, acc[qt], 0, 0, 0);
      }
    }
  }
#pragma unroll
  for (int jj = 0; jj < 4; ++jj) {
    float a = np2a[jj], bb = nq2a[jj];
#pragma unroll
    for (int m = 1; m < 16; m <<= 1) {
      a += __shfl_xor(a, m);
      bb += __shfl_xor(bb, m);
    }
    if ((t & 15) == 0) {
      int s = (t >> 4) + 16 * jj;
      S.pn2[s] = a;
      S.qn2[s] = bb;
    }
  }
  __syncthreads();
  // C/D: row = quad*4+r (p_local), col = lane&15 (q_local) [m89/m91 verified]
  float pnv[4];
#pragma unroll
  for (int r = 0; r < 4; ++r) pnv[r] = sqrtf(S.pn2[16 * w + quad * 4 + r]);
  float rowm[4] = {NEG_INF, NEG_INF, NEG_INF, NEG_INF};
#pragma unroll
  for (int qt = 0; qt < 4; ++qt) {
    float qnv = sqrtf(S.qn2[16 * qt + col]);
    float cmv = NEG_INF;
#pragma unroll
    for (int r = 0; r < 4; ++r) {
      float c = acc[qt][r] / (pnv[r] * qnv);    // no EPS in reference maxpool
      rowm[r] = fmaxf(rowm[r], c);
      cmv = fmaxf(cmv, c);
    }
    cmv = fmaxf(cmv, __shfl_xor(cmv, 16));
    cmv = fmaxf(cmv, __shfl_xor(cmv, 32));
    if (quad == 0) S.colp[w][16 * qt + col] = cmv;
  }
#pragma unroll
  for (int m = 1; m < 16; m <<= 1)
#pragma unroll
    for (int r = 0; r < 4; ++r) rowm[r] = fmaxf(rowm[r], __shfl_xor(rowm[r], m));
  if (col == 0) {
#pragma unroll
    for (int r = 0; r < 4; ++r) {
      int p = 16 * w + quad * 4 + r;
      out[((size_t)b * S_ + p) * ROW_ + (2 + dir) * L_ + l] = rowm[r];
    }
  }
  __syncthreads();
  if (t < S_) {
    float m0 = fmaxf(fmaxf(S.colp[0][t], S.colp[1][t]), fmaxf(S.colp[2][t], S.colp[3][t]));
    out[OUTQ_OFF + ((size_t)b * S_ + t) * ROW_ + (2 + dir) * L_ + l] = m0;
  }
}

// ---------------- K1: cos + w^2 prep + maxpool, all independent, one launch.
__global__ __launch_bounds__(256) void k1(const float* __restrict__ P,
                                          const float* __restrict__ Q,
                                          const float* __restrict__ Wf,
                                          float* __restrict__ w2r,
                                          float* __restrict__ cosM,
                                          float* __restrict__ sumpart,
                                          float* __restrict__ sum_q,
                                          float* __restrict__ out) {
  extern __shared__ char smem[];
  int bid = blockIdx.x;
  if (bid < NB_COS) {
    cos_body(smem, bid, P, Q, cosM, sumpart, sum_q);
  } else if (bid < NB_COS + NB_W) {
    int i = (bid - NB_COS) * 256 + threadIdx.x;
    if (i < 8 * L_ * H_) {
      float v = Wf[i];
      w2r[i] = v * v;
    }
  } else {
    maxpool_body(smem, bid - (NB_COS + NB_W), P, Q, Wf, out);
  }
}

// ---------------- K2: attentive + full outputs (homogeneous)
#define SG 4
struct OutsS {                      // 31264 B (occupancy bound: 5/CU)
  float u[600];
  float xP[SG][H_], xQ[SG][H_];
  float vmq[SG][H_], vmp[SG][H_], vxq[SG][H_], vxp[SG][H_];
  float sps[SG], sqs[SG];
};

__global__ __launch_bounds__(256) void k2(const float* __restrict__ P,
                                          const float* __restrict__ Q,
                                          const float* __restrict__ w2r,
                                          const float* __restrict__ cosM,
                                          const float* __restrict__ sumpart,
                                          const float* __restrict__ sum_q,
                                          float* __restrict__ out) {
  extern __shared__ char smem[];
  OutsS& S = *(OutsS*)smem;
  int bid = blockIdx.x;
  // XCD swizzle: bd = (bid&7) + 8*((bid>>3)&7); sg = bid>>6
  int x = bid & 7, j = bid >> 3;
  int bd = x + 8 * (j & 7);
  int sg = j >> 3;
  int s0 = sg * SG;
  int b = bd >> 1, dir = bd & 1;
  int t = threadIdx.x;
  // cos staged TRANSPOSED + interleaved: cosT[k][si] = cosC, cosT[k][4+si] = cosR
  float (*cosT)[8] = (float (*)[8])&S.u[0];     // 512 floats in u[600]
  const float* cm = cosM + (size_t)bd * S_ * S_;
  for (int idx = t; idx < S_ * 8; idx += 256) {
    int k = idx >> 3, jj = idx & 7, si = jj & 3;
    cosT[k][jj] = (jj < 4) ? cm[(size_t)k * S_ + s0 + si]
                           : cm[(size_t)(s0 + si) * S_ + k];
  }
  if (t < SG) {
    float a = 0.f;
    for (int pg = 0; pg < 16; ++pg) a += sumpart[((size_t)bd * 16 + pg) * S_ + s0 + t];
    S.sps[t] = a;
    S.sqs[t] = sum_q[bd * S_ + s0 + t];
  }
  int tgt = dir ? 0 : S_ - 1;
  const float* Pb = P + (size_t)b * S_ * H2_ + dir * H_;
  const float* Qb = Q + (size_t)b * S_ * H2_ + dir * H_;
  for (int g = t; g < SG * 75; g += 256) {
    int si = g / 75, c4 = g - si * 75;
    *(float4v*)&S.xP[si][4 * c4] = *(const float4v*)&Pb[(size_t)(s0 + si) * H2_ + 4 * c4];
    *(float4v*)&S.xQ[si][4 * c4] = *(const float4v*)&Qb[(size_t)(s0 + si) * H2_ + 4 * c4];
  }
  __syncthreads();
  for (int h = t; h < H_; h += 256) {
    float amp[SG], amq[SG], axp[SG], axq[SG];
#pragma unroll
    for (int si = 0; si < SG; ++si) { amp[si] = 0.f; amq[si] = 0.f; axp[si] = NEG_INF; axq[si] = NEG_INF; }
    for (int k = 0; k < S_; k += 2) {
      float pv0 = Pb[(size_t)k * H2_ + h];
      float qv0 = Qb[(size_t)k * H2_ + h];
      float pv1 = Pb[(size_t)(k + 1) * H2_ + h];
      float qv1 = Qb[(size_t)(k + 1) * H2_ + h];
      float4v cc0 = *(const float4v*)&cosT[k][0];
      float4v cr0 = *(const float4v*)&cosT[k][4];
      float4v cc1 = *(const float4v*)&cosT[k + 1][0];
      float4v cr1 = *(const float4v*)&cosT[k + 1][4];
#pragma unroll
      for (int si = 0; si < SG; ++si) {
        float t1 = pv0 * cc0[si];
        amp[si] += t1; axp[si] = fmaxf(axp[si], t1);
        float t2 = qv0 * cr0[si];
        amq[si] += t2; axq[si] = fmaxf(axq[si], t2);
        float t3 = pv1 * cc1[si];
        amp[si] += t3; axp[si] = fmaxf(axp[si], t3);
        float t4 = qv1 * cr1[si];
        amq[si] += t4; axq[si] = fmaxf(axq[si], t4);
      }
    }
#pragma unroll
    for (int si = 0; si < SG; ++si) {
      S.vmq[si][h] = amq[si] / S.sqs[si];
      S.vmp[si][h] = amp[si] / S.sps[si];
      S.vxq[si][h] = axq[si];
      S.vxp[si][h] = axp[si];
    }
  }
  __syncthreads();
  float* tq = &S.u[0];
  float* tp = &S.u[300];
  if (t < 75) {
    *(float4v*)&tq[4 * t] = *(const float4v*)&Qb[(size_t)tgt * H2_ + 4 * t];
    *(float4v*)&tp[4 * t] = *(const float4v*)&Pb[(size_t)tgt * H2_ + 4 * t];
  }
  __syncthreads();
  // 480 jobs, remapped so lanes share l -> w2r reads become few broadcasts.
  const int wb_[6] = {0, 0, 4, 4, 6, 6};
#pragma unroll
  for (int r = 0; r < 2; ++r) {
    int job = t + 256 * r;
    if (job < 480) {
      int l = job / 24;
      int g = job - l * 24;
      int pr = g >> 2, si = g & 3;
      const float* xv = (pr & 1) ? S.xQ[si] : S.xP[si];
      const float* y;
      if (pr == 0) y = tq;
      else if (pr == 1) y = tp;
      else if (pr == 2) y = S.vmq[si];
      else if (pr == 3) y = S.vmp[si];
      else if (pr == 4) y = S.vxq[si];
      else y = S.vxp[si];
      int widx = wb_[pr] + dir;
      const float* wp = w2r + (size_t)widx * (L_ * H_) + (size_t)l * H_;   // row layout
      float a1 = 0.f, a2 = 0.f, a3 = 0.f;
      for (int h4 = 0; h4 < H_; h4 += 4) {
        float4v wv = *(const float4v*)&wp[h4];
        float4v xx = *(const float4v*)&xv[h4];
        float4v yy = *(const float4v*)&y[h4];
#pragma unroll
        for (int jj = 0; jj < 4; ++jj) {
          float wx = wv[jj] * xx[jj];
          a1 = fmaf(wx, yy[jj], a1);
          a2 = fmaf(wx, xx[jj], a2);
          a3 = fmaf(wv[jj] * yy[jj], yy[jj], a3);
        }
      }
      float den = fmaxf(sqrtf(a2) * sqrtf(a3), 1e-8f);   // EPS per _mp_cos
      float c = a1 / den;
      int s = s0 + si;
      size_t base = ((pr & 1) ? OUTQ_OFF : 0) + ((size_t)b * S_ + s) * ROW_;
      out[base + (size_t)widx * L_ + l] = c;
    }
  }
}

extern "C" void kernel_launch(void* const* d_in, const int* in_sizes, int n_in,
                              void* d_out, int out_size, void* d_ws, size_t ws_size,
                              hipStream_t stream) {
  (void)out_size; (void)ws_size;
  int iw = 2;
  for (int i = 0; i < n_in; ++i) if (in_sizes[i] == 8 * L_ * H_) iw = i;
  int io[2] = {0, 1}, k = 0;
  for (int i = 0; i < n_in && k < 2; ++i) if (i != iw) io[k++] = i;
  const float* P  = (const float*)d_in[io[0]];
  const float* Q  = (const float*)d_in[io[1]];
  const float* Wf = (const float*)d_in[iw];
  float* out = (float*)d_out;

  float* ws = (float*)d_ws;             // ~1.52 MB
  float* w2r     = ws;                  // 48000
  float* cosM    = w2r + 48000;         // 262144
  float* sumpart = cosM + 262144;       // 65536 (64 bd * 16 pg * 64 q)
  float* sum_q   = sumpart + 65536;     // 4096

  size_t sh1 = sizeof(CosS) > sizeof(MaxpoolS) ? sizeof(CosS) : sizeof(MaxpoolS);
  k1<<<NB_COS + NB_W + NB_MP, 256, sh1, stream>>>(P, Q, Wf, w2r, cosM, sumpart, sum_q, out);
  k2<<<B_ * 2 * 16, 256, sizeof(OutsS), stream>>>(P, Q, w2r, cosM, sumpart, sum_q, out);
}